// Round 10
// baseline (23.618 us; speedup 1.0000x reference)
//
#include <hip/hip_runtime.h>

#define NQ 5
#define DIM 32
#define NL 4
#define NFEAT 30
#define NGATES (NL * NQ)

typedef float f32x4 __attribute__((ext_vector_type(4)));
typedef float f32x2 __attribute__((ext_vector_type(2)));
typedef short bf16x8 __attribute__((ext_vector_type(8)));

// round-to-nearest-even f32 -> bf16 (build kernel only)
static __device__ __forceinline__ unsigned short f2bf(float f) {
    unsigned u = __float_as_uint(f);
    u += 0x7FFFu + ((u >> 16) & 1u);
    return (unsigned short)(u >> 16);
}

// v_cvt_pk_bf16_f32: dword = { lo = bf16(a), hi = bf16(b) }, RNE (HW-validated)
static __device__ __forceinline__ unsigned cvt_pk_bf16(float a, float b) {
    unsigned d;
    asm("v_cvt_pk_bf16_f32 %0, %1, %2" : "=v"(d) : "v"(a), "v"(b));
    return d;
}

// ---------------------------------------------------------------------------
// Kernel 1: build the padded 64x32 bf16 matrix Upad from the 60 weights.
// 8 blocks x 128 threads; block b evolves columns 4b..4b+3.
//   Upad[R][k]: R = 2z + (0:Re,1:Im),  k = feature j.  Row-major bf16.
// ---------------------------------------------------------------------------
__global__ __launch_bounds__(128) void build_unitary(const float* __restrict__ W,
                                                     unsigned short* __restrict__ Ubf) {
    __shared__ __align__(16) float g[NGATES][8];

    const int t = threadIdx.x;
    if (t < NGATES) {
        const float phi = W[t * 3 + 0];
        const float th  = W[t * 3 + 1];
        const float om  = W[t * 3 + 2];
        const float c = cosf(0.5f * th), s = sinf(0.5f * th);
        const float a  = 0.5f * (phi + om);
        const float bb = 0.5f * (phi - om);
        const float epr = cosf(a),  epi = -sinf(a);
        const float emr = cosf(bb), emi = -sinf(bb);
        g[t][0] = epr * c;   g[t][1] = epi * c;    // u00
        g[t][2] = -emr * s;  g[t][3] = emi * s;    // u01
        g[t][4] = emr * s;   g[t][5] = emi * s;    // u10
        g[t][6] = epr * c;   g[t][7] = -epi * c;   // u11
    }
    __syncthreads();

    const int z = t & 31;
    const int j = blockIdx.x * 4 + (t >> 5);

    float ar = (z == j) ? 1.0f : 0.0f;
    float ai = 0.0f;

#pragma unroll
    for (int l = 0; l < NL; ++l) {
#pragma unroll
        for (int w = 0; w < NQ; ++w) {
            const int gi = l * NQ + w;
            const f32x4 glo = *reinterpret_cast<const f32x4*>(&g[gi][0]);
            const f32x4 ghi = *reinterpret_cast<const f32x4*>(&g[gi][4]);
            const int shift = 4 - w;
            const int msk = 1 << shift;
            const int bit = (z >> shift) & 1;
            const float pr = __shfl_xor(ar, msk, 32);
            const float pi = __shfl_xor(ai, msk, 32);
            const float csr = bit ? ghi.z : glo.x;
            const float csi = bit ? ghi.w : glo.y;
            const float cpr = bit ? ghi.x : glo.z;
            const float cpi = bit ? ghi.y : glo.w;
            const float nar = csr * ar - csi * ai + cpr * pr - cpi * pi;
            const float nai = csr * ai + csi * ar + cpr * pi + cpi * pr;
            ar = nar; ai = nai;
        }
        const int r = (l % (NQ - 1)) + 1;
#pragma unroll
        for (int cq = 0; cq < NQ; ++cq) {
            const int tq = (cq + r) % NQ;
            const int cs = 4 - cq, ts = 4 - tq;
            const int tmask = 1 << ts;
            const float pr = __shfl_xor(ar, tmask, 32);
            const float pi = __shfl_xor(ai, tmask, 32);
            const int ctrl = (z >> cs) & 1;
            ar = ctrl ? pr : ar;
            ai = ctrl ? pi : ai;
        }
    }

    Ubf[(2 * z + 0) * 32 + j] = f2bf(ar);
    Ubf[(2 * z + 1) * 32 + j] = f2bf(ai);
}

// ---------------------------------------------------------------------------
// Kernel 2: MFMA batched matvec — cross-tile pipelined, wave-private, NT.
// 512 blocks x 256 threads; block handles 4 consecutive tiles of 256 samples.
// Double-buffered LDS (2 x 30720 B); per tile each wave issues 8 NT
// global_load_lds dwordx4 into its private slice of the NEXT buffer, then a
// counted s_waitcnt vmcnt(8) (loads-only stream) so compute on tile i
// overlaps the in-flight loads of tile i+1. Zero barriers.
// CRITICAL: the stage guard fi < 64*NFEAT keeps iteration 7 half-masked
// (lanes 0..31) so no wave writes past its 1920-float slice — dropping it
// was R9's cross-buffer race (wave 3 corrupted buf^1 wave-0 slice mid-read).
// Outputs held in VGPRs (lane g keeps piece w=g; g0 also w=4), NT-stored in
// the epilogue after the final wait.
// D layout: col=lane&15=sample, row=(lane>>4)*4+reg; lane's 4 regs per
// A-tile t = 2 complex amplitudes z0=8t+2g (Re,Im), z1=z0+1.
// ---------------------------------------------------------------------------
__global__ __launch_bounds__(256) void qforward(const float* __restrict__ X,
                                                const unsigned short* __restrict__ Ubf,
                                                float* __restrict__ out, int B) {
    __shared__ __align__(16) float xs[2][4 * 64 * NFEAT];   // 2 x 30720 B
    const int tid  = threadIdx.x;
    const int lane = tid & 63;
    const int g    = lane >> 4;
    const int r    = lane & 15;
    const int wv   = tid >> 6;

    const int ntiles = (B + 255) >> 8;
    const int t0 = blockIdx.x * 4;

    // A fragments first (oldest in the vmcnt stream; covered by first wait)
    bf16x8 afrag[4];
#pragma unroll
    for (int t = 0; t < 4; ++t)
        afrag[t] = *reinterpret_cast<const bf16x8*>(Ubf + (16 * t + r) * 32 + g * 8);

    const long Btot = (long)B * NFEAT;

    // stage tile -> buffer (8 x NT global_load_lds dwordx4, wave-private slice)
    auto stage = [&](int tile, int buf) {
        if (tile >= ntiles) return;
        const long gbase = (long)tile * (256 * NFEAT) + wv * (64 * NFEAT);
        float* lb = &xs[buf][wv * (64 * NFEAT)];
#pragma unroll
        for (int it = 0; it < 8; ++it) {
            const int fi = it * 256 + lane * 4;
            if (fi < 64 * NFEAT && gbase + fi + 4 <= Btot)   // in-slice guard (R9 bug fix)
                __builtin_amdgcn_global_load_lds(
                    (const __attribute__((address_space(1))) unsigned*)(X + gbase + fi),
                    (__attribute__((address_space(3))) unsigned*)(lb + fi),
                    16, 0, 2 /* NT */);
        }
    };

    const float sg2 = (g & 2) ? -1.f : 1.f;   // wire2 sign: bit2 of z0
    const float sg3 = (g & 1) ? -1.f : 1.f;   // wire3 sign: bit1 of z0

    float oA[4][4], oB[4][4];   // per (tile-slot, sub-tile): this lane's output piece(s)

#define COMPUTE_TILE(I)                                                          \
    {                                                                            \
        const float* lbase = &xs[(I) & 1][wv * (64 * NFEAT)];                    \
        _Pragma("unroll")                                                        \
        for (int st = 0; st < 4; ++st) {                                         \
            const float* rowp = lbase + (st * 16 + r) * NFEAT + g * 8;           \
            f32x2 v0 = *reinterpret_cast<const f32x2*>(rowp + 0);                \
            f32x2 v1 = *reinterpret_cast<const f32x2*>(rowp + 2);                \
            f32x2 v2 = *reinterpret_cast<const f32x2*>(rowp + 4);                \
            f32x2 v3 = (g == 3) ? (f32x2){0.f, 0.f}                              \
                                : *reinterpret_cast<const f32x2*>(rowp + 6);     \
            bf16x8 bfrag;                                                        \
            unsigned* bw = reinterpret_cast<unsigned*>(&bfrag);                  \
            bw[0] = cvt_pk_bf16(v0.x, v0.y);                                     \
            bw[1] = cvt_pk_bf16(v1.x, v1.y);                                     \
            bw[2] = cvt_pk_bf16(v2.x, v2.y);                                     \
            bw[3] = cvt_pk_bf16(v3.x, v3.y);                                     \
            f32x4 d[4];                                                          \
            _Pragma("unroll")                                                    \
            for (int t = 0; t < 4; ++t)                                          \
                d[t] = __builtin_amdgcn_mfma_f32_16x16x32_bf16(                  \
                    afrag[t], bfrag, (f32x4){0.f, 0.f, 0.f, 0.f}, 0, 0, 0);      \
            float ev0 = 0.f, ev1 = 0.f, ev2 = 0.f, ev3 = 0.f, ev4 = 0.f,         \
                  nrm = 0.f;                                                     \
            _Pragma("unroll")                                                    \
            for (int t = 0; t < 4; ++t) {                                        \
                const float p0 = d[t].x * d[t].x + d[t].y * d[t].y;              \
                const float p1 = d[t].z * d[t].z + d[t].w * d[t].w;              \
                const float pt = p0 + p1;                                        \
                nrm += pt;                                                       \
                ev0 += (t & 2) ? -pt : pt;                                       \
                ev1 += (t & 1) ? -pt : pt;                                       \
                ev2 = fmaf(sg2, pt, ev2);                                        \
                ev3 = fmaf(sg3, pt, ev3);                                        \
                ev4 += p0 - p1;                                                  \
            }                                                                    \
            ev0 += __shfl_xor(ev0, 16, 64); ev0 += __shfl_xor(ev0, 32, 64);      \
            ev1 += __shfl_xor(ev1, 16, 64); ev1 += __shfl_xor(ev1, 32, 64);      \
            ev2 += __shfl_xor(ev2, 16, 64); ev2 += __shfl_xor(ev2, 32, 64);      \
            ev3 += __shfl_xor(ev3, 16, 64); ev3 += __shfl_xor(ev3, 32, 64);      \
            ev4 += __shfl_xor(ev4, 16, 64); ev4 += __shfl_xor(ev4, 32, 64);      \
            nrm += __shfl_xor(nrm, 16, 64); nrm += __shfl_xor(nrm, 32, 64);      \
            const float inv = 1.0f / nrm;                                        \
            const float mine = (g == 0) ? ev0 : (g == 1) ? ev1                   \
                             : (g == 2) ? ev2 : ev3;                             \
            oA[(I)][st] = mine * inv;                                            \
            oB[(I)][st] = ev4 * inv;                                             \
        }                                                                        \
    }

    // ---- software pipeline: loads-only counted vmcnt, no barriers ----
    stage(t0 + 0, 0);
    stage(t0 + 1, 1);
    asm volatile("s_waitcnt vmcnt(8)" ::: "memory");   // afrag + tile0 done
    __builtin_amdgcn_sched_barrier(0);
    COMPUTE_TILE(0)
    asm volatile("" ::: "memory");
    stage(t0 + 2, 0);
    asm volatile("s_waitcnt vmcnt(8)" ::: "memory");   // tile1 done
    __builtin_amdgcn_sched_barrier(0);
    COMPUTE_TILE(1)
    asm volatile("" ::: "memory");
    stage(t0 + 3, 1);
    asm volatile("s_waitcnt vmcnt(8)" ::: "memory");   // tile2 done
    __builtin_amdgcn_sched_barrier(0);
    COMPUTE_TILE(2)
    asm volatile("s_waitcnt vmcnt(0)" ::: "memory");   // tile3 done
    __builtin_amdgcn_sched_barrier(0);
    COMPUTE_TILE(3)
#undef COMPUTE_TILE

    // ---- epilogue: NT stores, outside the counted-load window ----
#pragma unroll
    for (int i = 0; i < 4; ++i) {
#pragma unroll
        for (int st = 0; st < 4; ++st) {
            const int s = (t0 + i) * 256 + wv * 64 + st * 16 + r;
            if (s < B) {
                __builtin_nontemporal_store(oA[i][st], &out[s * NQ + g]);
                if (g == 0)
                    __builtin_nontemporal_store(oB[i][st], &out[s * NQ + 4]);
            }
        }
    }
}

extern "C" void kernel_launch(void* const* d_in, const int* in_sizes, int n_in,
                              void* d_out, int out_size, void* d_ws, size_t ws_size,
                              hipStream_t stream) {
    const float* X = (const float*)d_in[0];
    const float* W = (const float*)d_in[1];
    float* out = (float*)d_out;
    const int B = in_sizes[0] / NFEAT;

    unsigned short* Ubf = (unsigned short*)d_ws;   // 64x32 bf16 = 4 KB

    build_unitary<<<8, 128, 0, stream>>>(W, Ubf);

    const int ntiles = (B + 255) / 256;
    const int nblocks = (ntiles + 3) / 4;
    qforward<<<nblocks, 256, 0, stream>>>(X, Ubf, out, B);
}

// Round 11
// 21.947 us; speedup vs baseline: 1.0762x; 1.0762x over previous
//
#include <hip/hip_runtime.h>

#define NQ 5
#define DIM 32
#define NL 4
#define NFEAT 30
#define NGATES (NL * NQ)

typedef float f32x4 __attribute__((ext_vector_type(4)));
typedef float f32x2 __attribute__((ext_vector_type(2)));
typedef short bf16x8 __attribute__((ext_vector_type(8)));

// round-to-nearest-even f32 -> bf16 (build kernel only)
static __device__ __forceinline__ unsigned short f2bf(float f) {
    unsigned u = __float_as_uint(f);
    u += 0x7FFFu + ((u >> 16) & 1u);
    return (unsigned short)(u >> 16);
}

// v_cvt_pk_bf16_f32: dword = { lo = bf16(a), hi = bf16(b) }, RNE (HW-validated)
static __device__ __forceinline__ unsigned cvt_pk_bf16(float a, float b) {
    unsigned d;
    asm("v_cvt_pk_bf16_f32 %0, %1, %2" : "=v"(d) : "v"(a), "v"(b));
    return d;
}

// ---------------------------------------------------------------------------
// Kernel 1: build the padded 64x32 bf16 matrix Upad from the 60 weights.
// 8 blocks x 128 threads; block b evolves columns 4b..4b+3.
//   Upad[R][k]: R = 2z + (0:Re,1:Im),  k = feature j.  Row-major bf16.
// ---------------------------------------------------------------------------
__global__ __launch_bounds__(128) void build_unitary(const float* __restrict__ W,
                                                     unsigned short* __restrict__ Ubf) {
    __shared__ __align__(16) float g[NGATES][8];

    const int t = threadIdx.x;
    if (t < NGATES) {
        const float phi = W[t * 3 + 0];
        const float th  = W[t * 3 + 1];
        const float om  = W[t * 3 + 2];
        const float c = cosf(0.5f * th), s = sinf(0.5f * th);
        const float a  = 0.5f * (phi + om);
        const float bb = 0.5f * (phi - om);
        const float epr = cosf(a),  epi = -sinf(a);
        const float emr = cosf(bb), emi = -sinf(bb);
        g[t][0] = epr * c;   g[t][1] = epi * c;    // u00
        g[t][2] = -emr * s;  g[t][3] = emi * s;    // u01
        g[t][4] = emr * s;   g[t][5] = emi * s;    // u10
        g[t][6] = epr * c;   g[t][7] = -epi * c;   // u11
    }
    __syncthreads();

    const int z = t & 31;
    const int j = blockIdx.x * 4 + (t >> 5);

    float ar = (z == j) ? 1.0f : 0.0f;
    float ai = 0.0f;

#pragma unroll
    for (int l = 0; l < NL; ++l) {
#pragma unroll
        for (int w = 0; w < NQ; ++w) {
            const int gi = l * NQ + w;
            const f32x4 glo = *reinterpret_cast<const f32x4*>(&g[gi][0]);
            const f32x4 ghi = *reinterpret_cast<const f32x4*>(&g[gi][4]);
            const int shift = 4 - w;
            const int msk = 1 << shift;
            const int bit = (z >> shift) & 1;
            const float pr = __shfl_xor(ar, msk, 32);
            const float pi = __shfl_xor(ai, msk, 32);
            const float csr = bit ? ghi.z : glo.x;
            const float csi = bit ? ghi.w : glo.y;
            const float cpr = bit ? ghi.x : glo.z;
            const float cpi = bit ? ghi.y : glo.w;
            const float nar = csr * ar - csi * ai + cpr * pr - cpi * pi;
            const float nai = csr * ai + csi * ar + cpr * pi + cpi * pr;
            ar = nar; ai = nai;
        }
        const int r = (l % (NQ - 1)) + 1;
#pragma unroll
        for (int cq = 0; cq < NQ; ++cq) {
            const int tq = (cq + r) % NQ;
            const int cs = 4 - cq, ts = 4 - tq;
            const int tmask = 1 << ts;
            const float pr = __shfl_xor(ar, tmask, 32);
            const float pi = __shfl_xor(ai, tmask, 32);
            const int ctrl = (z >> cs) & 1;
            ar = ctrl ? pr : ar;
            ai = ctrl ? pi : ai;
        }
    }

    Ubf[(2 * z + 0) * 32 + j] = f2bf(ar);
    Ubf[(2 * z + 1) * 32 + j] = f2bf(ai);
}

// ---------------------------------------------------------------------------
// Kernel 2: MFMA batched matvec — depth-2 pipeline at FULL occupancy.
// Tile = 128 samples (15360 B); double-buffered LDS = 30720 B total ->
// 5 blocks/CU = 20 waves/CU (R8's TLP) AND cross-tile overlap (R10's ILP).
// 1024 blocks x 4 tiles. Per tile each wave issues 4 NT global_load_lds
// dwordx4 into its private slice of the next buffer; counted vmcnt(4)
// keeps the next tile's loads in flight under compute. One cold drain per
// block (tile 0) instead of per tile. Zero barriers. Stage guard
// fi < 32*NFEAT keeps it=3 lane-masked (lanes 0..47) inside the 960-float
// slice (R9 lesson). Non-full tail blocks take a serial vmcnt(0) path.
// D layout: col=lane&15=sample, row=(lane>>4)*4+reg; lane's 4 regs per
// A-tile t = 2 complex amplitudes z0=8t+2g (Re,Im), z1=z0+1.
// Outputs in VGPRs (lane g keeps w=g; g0 also w=4), NT-stored in epilogue.
// ---------------------------------------------------------------------------
__global__ __launch_bounds__(256, 5) void qforward(const float* __restrict__ X,
                                                   const unsigned short* __restrict__ Ubf,
                                                   float* __restrict__ out, int B) {
    __shared__ __align__(16) float xs[2][4 * 32 * NFEAT];   // 2 x 15360 B
    const int tid  = threadIdx.x;
    const int lane = tid & 63;
    const int g    = lane >> 4;
    const int r    = lane & 15;
    const int wv   = tid >> 6;

    const int ntiles = (B + 127) >> 7;      // 128-sample tiles
    const int t0 = blockIdx.x * 4;

    // A fragments first (oldest in the vmcnt stream; drained by first wait)
    bf16x8 afrag[4];
#pragma unroll
    for (int t = 0; t < 4; ++t)
        afrag[t] = *reinterpret_cast<const bf16x8*>(Ubf + (16 * t + r) * 32 + g * 8);
    __builtin_amdgcn_sched_barrier(0);       // pin afrag loads before stage0

    const long Btot = (long)B * NFEAT;

    // stage tile -> buffer (4 x NT global_load_lds dwordx4, wave-private slice)
    auto stage = [&](int tile, int buf) {
        const long gbase = (long)tile * (128 * NFEAT) + wv * (32 * NFEAT);
        float* lb = &xs[buf][wv * (32 * NFEAT)];
#pragma unroll
        for (int it = 0; it < 4; ++it) {
            const int fi = it * 256 + lane * 4;
            if (fi < 32 * NFEAT && gbase + fi + 4 <= Btot)   // in-slice guard
                __builtin_amdgcn_global_load_lds(
                    (const __attribute__((address_space(1))) unsigned*)(X + gbase + fi),
                    (__attribute__((address_space(3))) unsigned*)(lb + fi),
                    16, 0, 2 /* NT */);
        }
    };

    const float sg2 = (g & 2) ? -1.f : 1.f;   // wire2 sign: bit2 of z0
    const float sg3 = (g & 1) ? -1.f : 1.f;   // wire3 sign: bit1 of z0

    float oA[4][2], oB[4][2];   // per (tile-slot, sub-tile): this lane's pieces

#define COMPUTE_TILE(I)                                                          \
    {                                                                            \
        const float* lbase = &xs[(I) & 1][wv * (32 * NFEAT)];                    \
        _Pragma("unroll")                                                        \
        for (int st = 0; st < 2; ++st) {                                         \
            const float* rowp = lbase + (st * 16 + r) * NFEAT + g * 8;           \
            f32x2 v0 = *reinterpret_cast<const f32x2*>(rowp + 0);                \
            f32x2 v1 = *reinterpret_cast<const f32x2*>(rowp + 2);                \
            f32x2 v2 = *reinterpret_cast<const f32x2*>(rowp + 4);                \
            f32x2 v3 = (g == 3) ? (f32x2){0.f, 0.f}                              \
                                : *reinterpret_cast<const f32x2*>(rowp + 6);     \
            bf16x8 bfrag;                                                        \
            unsigned* bw = reinterpret_cast<unsigned*>(&bfrag);                  \
            bw[0] = cvt_pk_bf16(v0.x, v0.y);                                     \
            bw[1] = cvt_pk_bf16(v1.x, v1.y);                                     \
            bw[2] = cvt_pk_bf16(v2.x, v2.y);                                     \
            bw[3] = cvt_pk_bf16(v3.x, v3.y);                                     \
            f32x4 d[4];                                                          \
            _Pragma("unroll")                                                    \
            for (int t = 0; t < 4; ++t)                                          \
                d[t] = __builtin_amdgcn_mfma_f32_16x16x32_bf16(                  \
                    afrag[t], bfrag, (f32x4){0.f, 0.f, 0.f, 0.f}, 0, 0, 0);      \
            float ev0 = 0.f, ev1 = 0.f, ev2 = 0.f, ev3 = 0.f, ev4 = 0.f,         \
                  nrm = 0.f;                                                     \
            _Pragma("unroll")                                                    \
            for (int t = 0; t < 4; ++t) {                                        \
                const float p0 = d[t].x * d[t].x + d[t].y * d[t].y;              \
                const float p1 = d[t].z * d[t].z + d[t].w * d[t].w;              \
                const float pt = p0 + p1;                                        \
                nrm += pt;                                                       \
                ev0 += (t & 2) ? -pt : pt;                                       \
                ev1 += (t & 1) ? -pt : pt;                                       \
                ev2 = fmaf(sg2, pt, ev2);                                        \
                ev3 = fmaf(sg3, pt, ev3);                                        \
                ev4 += p0 - p1;                                                  \
            }                                                                    \
            ev0 += __shfl_xor(ev0, 16, 64); ev0 += __shfl_xor(ev0, 32, 64);      \
            ev1 += __shfl_xor(ev1, 16, 64); ev1 += __shfl_xor(ev1, 32, 64);      \
            ev2 += __shfl_xor(ev2, 16, 64); ev2 += __shfl_xor(ev2, 32, 64);      \
            ev3 += __shfl_xor(ev3, 16, 64); ev3 += __shfl_xor(ev3, 32, 64);      \
            ev4 += __shfl_xor(ev4, 16, 64); ev4 += __shfl_xor(ev4, 32, 64);      \
            nrm += __shfl_xor(nrm, 16, 64); nrm += __shfl_xor(nrm, 32, 64);      \
            const float inv = 1.0f / nrm;                                        \
            const float mine = (g == 0) ? ev0 : (g == 1) ? ev1                   \
                             : (g == 2) ? ev2 : ev3;                             \
            oA[(I)][st] = mine * inv;                                            \
            oB[(I)][st] = ev4 * inv;                                             \
        }                                                                        \
    }

    if (t0 + 4 <= ntiles) {
        // ---- full block: depth-2 pipeline, counted vmcnt, no barriers ----
        stage(t0 + 0, 0);
        stage(t0 + 1, 1);
        asm volatile("s_waitcnt vmcnt(4)" ::: "memory");   // afrag + tile0 done
        __builtin_amdgcn_sched_barrier(0);
        COMPUTE_TILE(0)
        asm volatile("" ::: "memory");
        stage(t0 + 2, 0);
        asm volatile("s_waitcnt vmcnt(4)" ::: "memory");   // tile1 done
        __builtin_amdgcn_sched_barrier(0);
        COMPUTE_TILE(1)
        asm volatile("" ::: "memory");
        stage(t0 + 3, 1);
        asm volatile("s_waitcnt vmcnt(4)" ::: "memory");   // tile2 done
        __builtin_amdgcn_sched_barrier(0);
        COMPUTE_TILE(2)
        asm volatile("s_waitcnt vmcnt(0)" ::: "memory");   // tile3 done
        __builtin_amdgcn_sched_barrier(0);
        COMPUTE_TILE(3)
    } else {
        // ---- tail block (rare): serial, fully drained per tile ----
        if (t0 + 0 < ntiles) {
            stage(t0 + 0, 0);
            asm volatile("s_waitcnt vmcnt(0)" ::: "memory");
            __builtin_amdgcn_sched_barrier(0);
            COMPUTE_TILE(0)
        }
        if (t0 + 1 < ntiles) {
            stage(t0 + 1, 1);
            asm volatile("s_waitcnt vmcnt(0)" ::: "memory");
            __builtin_amdgcn_sched_barrier(0);
            COMPUTE_TILE(1)
        }
        if (t0 + 2 < ntiles) {
            stage(t0 + 2, 0);
            asm volatile("s_waitcnt vmcnt(0)" ::: "memory");
            __builtin_amdgcn_sched_barrier(0);
            COMPUTE_TILE(2)
        }
        if (t0 + 3 < ntiles) {
            stage(t0 + 3, 1);
            asm volatile("s_waitcnt vmcnt(0)" ::: "memory");
            __builtin_amdgcn_sched_barrier(0);
            COMPUTE_TILE(3)
        }
    }
#undef COMPUTE_TILE

    // ---- epilogue: NT stores, outside the counted-load window ----
#pragma unroll
    for (int i = 0; i < 4; ++i) {
#pragma unroll
        for (int st = 0; st < 2; ++st) {
            const int s = (t0 + i) * 128 + wv * 32 + st * 16 + r;
            if (s < B) {
                __builtin_nontemporal_store(oA[i][st], &out[s * NQ + g]);
                if (g == 0)
                    __builtin_nontemporal_store(oB[i][st], &out[s * NQ + 4]);
            }
        }
    }
}

extern "C" void kernel_launch(void* const* d_in, const int* in_sizes, int n_in,
                              void* d_out, int out_size, void* d_ws, size_t ws_size,
                              hipStream_t stream) {
    const float* X = (const float*)d_in[0];
    const float* W = (const float*)d_in[1];
    float* out = (float*)d_out;
    const int B = in_sizes[0] / NFEAT;

    unsigned short* Ubf = (unsigned short*)d_ws;   // 64x32 bf16 = 4 KB

    build_unitary<<<8, 128, 0, stream>>>(W, Ubf);

    const int ntiles = (B + 127) / 128;
    const int nblocks = (ntiles + 3) / 4;
    qforward<<<nblocks, 256, 0, stream>>>(X, Ubf, out, B);
}